// Round 4
// baseline (402.213 us; speedup 1.0000x reference)
//
#include <hip/hip_runtime.h>
#include <math.h>

// Element-wise physics step, B = 8,388,608 rows, AoS row = 5 floats.
// v5: persistent grid-stride (Guideline 11). 2048 blocks x 256 threads,
// 16 rows/thread, software-pipelined: loads for row i+stride are issued
// BEFORE compute+store of row i, so every wave always has a full load
// round in flight -- MLP no longer depends on block churn. Access shape
// per-wave is identical to v1 (shape proven irrelevant in v2/v3/v4:
// identical 147.5/196.6 MB traffic, identical ~130 us).
// Numerics mirror numpy f32 op-by-op (no FMA contraction in the critical
// chain) so the reached_target boolean boundary matches the ref.

__global__ __launch_bounds__(256) void step_kernel(
    const float* __restrict__ x,        // (B,5)
    const float* __restrict__ a,        // (B,2)
    const float* __restrict__ noise,    // (B,2)
    const float* __restrict__ pro_gains,          // (2,)
    const float* __restrict__ pro_noise_ln_vars,  // (2,)
    const float* __restrict__ goal_radius,        // (1,)
    float* __restrict__ out_next,       // (B,5) at d_out
    float* __restrict__ out_reach,      // (B,)  at d_out + 5*B
    int n)
{
    const int stride = gridDim.x * blockDim.x;   // 524288
    int i = blockIdx.x * blockDim.x + threadIdx.x;
    if (i >= n) return;

    // Uniform scalars (uniform address -> scalar loads, hoisted).
    const float g0   = pro_gains[0];
    const float g1   = pro_gains[1];
    const float std0 = __fsqrt_rn(expf(pro_noise_ln_vars[0]));
    const float std1 = __fsqrt_rn(expf(pro_noise_ln_vars[1]));
    const float gr   = goal_radius[0];

    const float DT    = 0.1f;
    const float PI_F  = 3.14159265358979323846f;  // rounds to 3.14159274f
    const float TWOPI = 6.283185307179586f;       // rounds to 6.2831855f

    // ---- prologue: load row i ----
    float2 av = *(const float2*)(a + 2 * (size_t)i);
    float2 nv = *(const float2*)(noise + 2 * (size_t)i);
    float px0  = x[5 * (size_t)i + 0];
    float py0  = x[5 * (size_t)i + 1];
    float ang0 = x[5 * (size_t)i + 2];

    while (true) {
        // ---- issue next iteration's loads first (stay in flight across
        //      the compute below; compiler keeps them as early vmem) ----
        const int inext = i + stride;
        const bool have_next = inext < n;
        float2 av2, nv2;
        float px2 = 0.f, py2 = 0.f, ang2 = 0.f;
        av2.x = av2.y = nv2.x = nv2.y = 0.f;
        if (have_next) {
            const size_t sj = (size_t)inext;
            av2  = *(const float2*)(a + 2 * sj);
            nv2  = *(const float2*)(noise + 2 * sj);
            px2  = x[5 * sj + 0];
            py2  = x[5 * sj + 1];
            ang2 = x[5 * sj + 2];
        }

        // ---- compute row i (numpy f32 op-by-op) ----
        const float w0 = __fmul_rn(std0, nv.x);
        const float w1 = __fmul_rn(std1, nv.y);
        const float vel     = __fadd_rn(__fmul_rn(g0, av.x), w0);
        const float ang_vel = __fadd_rn(__fmul_rn(g1, av.y), w1);

        // ang = mod(ang0 + ang_vel*DT + pi, 2pi) - pi (numpy mod: divisor sign)
        const float t  = __fadd_rn(ang0, __fmul_rn(ang_vel, DT));
        const float tp = __fadd_rn(t, PI_F);
        float m = fmodf(tp, TWOPI);
        if (m < 0.0f) m = __fadd_rn(m, TWOPI);
        const float ang = __fsub_rn(m, PI_F);

        float s, c;
        sincosf(ang, &s, &c);  // accurate variant (~2 ulp), matches np closely

        float px = __fadd_rn(px0, __fmul_rn(__fmul_rn(vel, c), DT));
        px = fminf(fmaxf(px, -1.0f), 1.0f);
        float py = __fadd_rn(py0, __fmul_rn(__fmul_rn(vel, s), DT));
        py = fminf(fmaxf(py, -1.0f), 1.0f);

        const float r2 = __fadd_rn(__fmul_rn(px, px), __fmul_rn(py, py));
        const float r  = __fsqrt_rn(r2);
        const float rch = (r <= gr) ? 1.0f : 0.0f;

        // ---- store row i ----
        const size_t si = (size_t)i;
        out_next[5 * si + 0] = px;
        out_next[5 * si + 1] = py;
        out_next[5 * si + 2] = ang;
        out_next[5 * si + 3] = vel;
        out_next[5 * si + 4] = ang_vel;
        out_reach[si] = rch;

        if (!have_next) break;
        i = inext;
        av = av2; nv = nv2; px0 = px2; py0 = py2; ang0 = ang2;
    }
}

extern "C" void kernel_launch(void* const* d_in, const int* in_sizes, int n_in,
                              void* d_out, int out_size, void* d_ws, size_t ws_size,
                              hipStream_t stream) {
    const float* x       = (const float*)d_in[0];
    const float* a       = (const float*)d_in[1];
    const float* noise   = (const float*)d_in[2];
    const float* gains   = (const float*)d_in[3];
    const float* lnvars  = (const float*)d_in[4];
    const float* gradius = (const float*)d_in[5];

    const int n = in_sizes[0] / 5;            // B
    float* out_next  = (float*)d_out;         // B*5 floats
    float* out_reach = (float*)d_out + (size_t)n * 5;  // B floats

    const int block = 256;
    // Guideline 11: memory-bound -> ~8 blocks/CU persistent, grid-stride.
    int grid = 2048;
    const long long total_threads_needed = ((long long)n + 0);
    if ((long long)grid * block > total_threads_needed)
        grid = (int)((total_threads_needed + block - 1) / block);
    if (grid < 1) grid = 1;
    step_kernel<<<grid, block, 0, stream>>>(x, a, noise, gains, lnvars, gradius,
                                            out_next, out_reach, n);
}